// Round 7
// baseline (257.741 us; speedup 1.0000x reference)
//
#include <hip/hip_runtime.h>
#include <cstdint>
#include <cstddef>

#define TOKENS 4096
#define DM 512
#define DF 2048
#define NE 8
#define NPAIR 8192  // TOKENS * TOPK
#define SPLIT 4     // split-K factor for GEMM2 (atomic accumulation)

typedef unsigned short u16;
typedef __attribute__((ext_vector_type(8))) short short8;
typedef __attribute__((ext_vector_type(4))) float f32x4;

// fp32 -> bf16 round-to-nearest-even (finite inputs only)
__device__ __forceinline__ u16 f2b(float x) {
  uint32_t u = __builtin_bit_cast(uint32_t, x);
  uint32_t r = (u + 0x7fffu + ((u >> 16) & 1u)) >> 16;
  return (u16)r;
}

__device__ __forceinline__ void gl_lds16(const void* gsrc, void* ldst) {
  __builtin_amdgcn_global_load_lds(
      (__attribute__((address_space(1))) void*)(gsrc),
      (__attribute__((address_space(3))) void*)(ldst), 16, 0, 0);
}

// ---------------- prep: one dispatch ----------------
// bid 0            : routing (+ pair_coef)
// bid 1..2048      : hidden fp32 -> bf16
// bid 2049..4096   : tr wi  [8][512][2048] -> [8][2048][512]
// bid 4097..6144   : tr wo  [8][2048][512] -> [8][512][2048]
// bid 6145..8192   : zero next[4096][512] f32
__global__ __launch_bounds__(256) void prep_kernel(
    const int* __restrict__ eidx, const float* __restrict__ prob,
    const float* __restrict__ hidden, u16* __restrict__ hidden_b,
    const float* __restrict__ wi, u16* __restrict__ wi_t,
    const float* __restrict__ wo, u16* __restrict__ wo_t,
    float* __restrict__ nxt,
    int* __restrict__ pair_token, int* __restrict__ pair_pos,
    float* __restrict__ pair_coef,
    int* __restrict__ seg_off, int* __restrict__ seg_cnt) {
  __shared__ __align__(16) float t[64][65];  // 16640 B; block 0 reuses the first ints
  int bid = blockIdx.x;
  int tid = threadIdx.x;
  if (bid == 0) {
    // --- routing (R6-proven body) + per-pair coefficient ---
    int* cnt = (int*)&t[0][0];
    int* off = cnt + 8;
    int* cur = cnt + 16;
    if (tid < NE) { cnt[tid] = 0; cur[tid] = 0; }
    __syncthreads();
    for (int i = tid; i < NPAIR; i += 256) atomicAdd(&cnt[eidx[i]], 1);
    __syncthreads();
    if (tid == 0) {
      int a = 0;
      for (int e = 0; e < NE; ++e) { off[e] = a; a += cnt[e]; }
    }
    __syncthreads();
    for (int i = tid; i < NPAIR; i += 256) {
      int e = eidx[i];
      int p = off[e] + atomicAdd(&cur[e], 1);
      pair_token[p] = i >> 1;  // token index
      pair_pos[i] = p;         // where this (token,k) landed
      pair_coef[p] = ((i & 1) ? 0.25f : 0.5f) * prob[i];  // df[k] * prob[t,k]
    }
    if (tid < NE) { seg_off[tid] = off[tid]; seg_cnt[tid] = cnt[tid]; }
  } else if (bid <= 2048) {
    // --- hidden cvt (R6-proven body) ---
    int i = (bid - 1) * 256 + tid;  // float4 group
    float4 v = ((const float4*)hidden)[i];
    ushort4 o;
    o.x = f2b(v.x); o.y = f2b(v.y); o.z = f2b(v.z); o.w = f2b(v.w);
    ((ushort4*)hidden_b)[i] = o;
  } else if (bid <= 4096) {
    // --- tr wi (R6-proven body) ---
    const int R = DM, C = DF;
    int f = bid - 2049;
    int e = f >> 8;
    int cb = (f & 31) * 64, rb = ((f >> 5) & 7) * 64;
    const float* s = wi + (size_t)e * R * C;
    u16* d = wi_t + (size_t)e * R * C;
    int r = tid >> 4, cq = tid & 15;
#pragma unroll
    for (int i = 0; i < 4; ++i) {
      float4 v = *(const float4*)&s[(size_t)(rb + r + 16 * i) * C + cb + cq * 4];
      t[r + 16 * i][cq * 4 + 0] = v.x;
      t[r + 16 * i][cq * 4 + 1] = v.y;
      t[r + 16 * i][cq * 4 + 2] = v.z;
      t[r + 16 * i][cq * 4 + 3] = v.w;
    }
    __syncthreads();
    int rq = tid & 15, c0 = tid >> 4;
#pragma unroll
    for (int i = 0; i < 4; ++i) {
      int c = c0 + 16 * i;
      ushort4 o;
      o.x = f2b(t[rq * 4 + 0][c]);
      o.y = f2b(t[rq * 4 + 1][c]);
      o.z = f2b(t[rq * 4 + 2][c]);
      o.w = f2b(t[rq * 4 + 3][c]);
      *(ushort4*)&d[(size_t)(cb + c) * R + rb + rq * 4] = o;
    }
  } else if (bid <= 6144) {
    // --- tr wo (R6-proven body) ---
    const int R = DF, C = DM;
    int f = bid - 4097;
    int e = f >> 8;
    int cb = (f & 7) * 64, rb = ((f >> 3) & 31) * 64;
    const float* s = wo + (size_t)e * R * C;
    u16* d = wo_t + (size_t)e * R * C;
    int r = tid >> 4, cq = tid & 15;
#pragma unroll
    for (int i = 0; i < 4; ++i) {
      float4 v = *(const float4*)&s[(size_t)(rb + r + 16 * i) * C + cb + cq * 4];
      t[r + 16 * i][cq * 4 + 0] = v.x;
      t[r + 16 * i][cq * 4 + 1] = v.y;
      t[r + 16 * i][cq * 4 + 2] = v.z;
      t[r + 16 * i][cq * 4 + 3] = v.w;
    }
    __syncthreads();
    int rq = tid & 15, c0 = tid >> 4;
#pragma unroll
    for (int i = 0; i < 4; ++i) {
      int c = c0 + 16 * i;
      ushort4 o;
      o.x = f2b(t[rq * 4 + 0][c]);
      o.y = f2b(t[rq * 4 + 1][c]);
      o.z = f2b(t[rq * 4 + 2][c]);
      o.w = f2b(t[rq * 4 + 3][c]);
      *(ushort4*)&d[(size_t)(cb + c) * R + rb + rq * 4] = o;
    }
  } else {
    // --- zero next ---
    int i = (bid - 6145) * 256 + tid;  // float4 group; 2048 blocks cover 8 MB
    float4 z = {0.f, 0.f, 0.f, 0.f};
    ((float4*)nxt)[i] = z;
  }
}

// ---------------- grouped GEMM, R6-proven K-loop (BK=32, z-grid) ----------------
// C[m][n] = sum_{k in [sp*ks, +ks)} A[row(m)][k] * Bt[n][k]; tile 128x128, 4 waves.
// blockIdx.x = (sp << sp_shift) | nt.
// RELU=true  : out_b[row][n] = bf16(relu(C))            (GEMM1 -> act)
// RELU=false : atomicAdd(nxt[token[row]][n], coef[row]*C)  (GEMM2 -> next)
template <int KDIM, bool GATHER, bool RELU>
__global__ __launch_bounds__(256) void gemm_kernel(
    const u16* __restrict__ A,         // [*, KDIM] bf16 rows
    const u16* __restrict__ Bt,        // [NE][n_total][KDIM] bf16
    const int* __restrict__ pair_token,
    const float* __restrict__ pair_coef,
    const int* __restrict__ seg_off, const int* __restrict__ seg_cnt,
    u16* __restrict__ out_b,           // act (RELU)
    float* __restrict__ nxt,           // next accumulator (!RELU)
    int n_total, int nt_mask, int sp_shift, int ks) {
  const int e = blockIdx.z;
  const int cnt = seg_cnt[e];
  const int mt = blockIdx.y;
  if (mt * 128 >= cnt) return;
  const int off = seg_off[e];
  const int nt = blockIdx.x & nt_mask;
  const int sp = blockIdx.x >> sp_shift;
  const int kb = sp * ks, ke = kb + ks;
  const int tid = threadIdx.x;
  const int wave = tid >> 6, lane = tid & 63;

  __shared__ __align__(16) u16 Al[128 * 32];
  __shared__ __align__(16) u16 Bl[128 * 32];

  const int r0 = wave * 32;
  const int rr = lane >> 2;
  const int cc = (lane & 3) * 8;  // element offset (8 bf16 = 16B)

  const u16* aSrc[2];
  const u16* bSrc[2];
  const u16* BtBase = Bt + ((size_t)e * n_total + (size_t)nt * 128) * KDIM;
#pragma unroll
  for (int g = 0; g < 2; ++g) {
    int rl = r0 + g * 16 + rr;
    int m = mt * 128 + rl;
    if (m > cnt - 1) m = cnt - 1;  // clamp padding rows to valid data
    int srow = GATHER ? pair_token[off + m] : (off + m);
    aSrc[g] = A + (size_t)srow * KDIM + cc;
    bSrc[g] = BtBase + (size_t)rl * KDIM + cc;
  }

  const int wm = wave >> 1, wn = wave & 1;
  const int rl16 = lane & 15;
  const int kk = (lane >> 4) * 8;

  f32x4 acc[4][4];
#pragma unroll
  for (int i = 0; i < 4; ++i)
#pragma unroll
    for (int j = 0; j < 4; ++j)
#pragma unroll
      for (int r = 0; r < 4; ++r) acc[i][j][r] = 0.0f;

  for (int k0 = kb; k0 < ke; k0 += 32) {
#pragma unroll
    for (int g = 0; g < 2; ++g) {
      gl_lds16(aSrc[g] + k0, &Al[(r0 + g * 16) * 32]);
      gl_lds16(bSrc[g] + k0, &Bl[(r0 + g * 16) * 32]);
    }
    __syncthreads();
    short8 af[4], bf[4];
#pragma unroll
    for (int mi = 0; mi < 4; ++mi)
      af[mi] = *(const short8*)&Al[(wm * 64 + mi * 16 + rl16) * 32 + kk];
#pragma unroll
    for (int ni = 0; ni < 4; ++ni)
      bf[ni] = *(const short8*)&Bl[(wn * 64 + ni * 16 + rl16) * 32 + kk];
#pragma unroll
    for (int mi = 0; mi < 4; ++mi)
#pragma unroll
      for (int ni = 0; ni < 4; ++ni)
        acc[mi][ni] = __builtin_amdgcn_mfma_f32_16x16x32_bf16(af[mi], bf[ni], acc[mi][ni], 0, 0, 0);
    __syncthreads();
  }

  // epilogue: D[row][col]: col = lane&15, row = (lane>>4)*4 + reg
  const int rowq = (lane >> 4) * 4;
#pragma unroll
  for (int mi = 0; mi < 4; ++mi) {
#pragma unroll
    for (int r = 0; r < 4; ++r) {
      int m = mt * 128 + wm * 64 + mi * 16 + rowq + r;
      if (m < cnt) {
        int p = off + m;
        if (RELU) {
          size_t rowp = (size_t)p * n_total;
#pragma unroll
          for (int ni = 0; ni < 4; ++ni) {
            int n = nt * 128 + wn * 64 + ni * 16 + rl16;
            float v = acc[mi][ni][r];
            v = v > 0.0f ? v : 0.0f;
            out_b[rowp + n] = f2b(v);
          }
        } else {
          float cf = pair_coef[p];
          float* rowp = nxt + (size_t)pair_token[p] * DM;
#pragma unroll
          for (int ni = 0; ni < 4; ++ni) {
            int n = nt * 128 + wn * 64 + ni * 16 + rl16;
            atomicAdd(&rowp[n], cf * acc[mi][ni][r]);
          }
        }
      }
    }
  }
}

// ---------------- combine: out = where(next != 0, next, hidden) ----------------
__global__ void combine_kernel(const float* __restrict__ hidden,
                               const float* __restrict__ nxt,
                               float* __restrict__ out) {
  int i = blockIdx.x * 256 + threadIdx.x;  // float4 group
  float4 r = ((const float4*)nxt)[i];
  float4 h = ((const float4*)hidden)[i];
  float4 o;
  o.x = (r.x != 0.0f) ? r.x : h.x;
  o.y = (r.y != 0.0f) ? r.y : h.y;
  o.z = (r.z != 0.0f) ? r.z : h.z;
  o.w = (r.w != 0.0f) ? r.w : h.w;
  ((float4*)out)[i] = o;
}

extern "C" void kernel_launch(void* const* d_in, const int* in_sizes, int n_in,
                              void* d_out, int out_size, void* d_ws, size_t ws_size,
                              hipStream_t stream) {
  const float* hidden = (const float*)d_in[0];
  const float* prob = (const float*)d_in[1];
  const float* wi = (const float*)d_in[2];
  const float* wo = (const float*)d_in[3];
  const int* eidx = (const int*)d_in[4];
  float* out = (float*)d_out;

  char* ws = (char*)d_ws;
  u16* hidden_b = (u16*)(ws + 0);                     //  4 MB [4096][512] bf16
  u16* wi_t = (u16*)(ws + ((size_t)4 << 20));         // 16 MB [8][2048][512] bf16 (wi^T)
  u16* wo_t = (u16*)(ws + ((size_t)20 << 20));        // 16 MB [8][512][2048] bf16 (wo^T)
  u16* act = (u16*)(ws + ((size_t)36 << 20));         // 32 MB [8192][2048] bf16
  float* nxt = (float*)(ws + ((size_t)68 << 20));     //  8 MB [4096][512] f32 accumulator
  char* smalls = ws + ((size_t)132 << 20);            // same proven offset as R6
  int* pair_token = (int*)(smalls);
  int* pair_pos = (int*)(smalls + (64u << 10));
  int* seg_off = (int*)(smalls + (128u << 10));
  int* seg_cnt = (int*)(smalls + (128u << 10) + 256);
  float* pair_coef = (float*)(smalls + (192u << 10));

  // 1) prep: routing | hidden cvt | tr wi | tr wo | zero next — one dispatch
  hipLaunchKernelGGL(prep_kernel, dim3(8193), dim3(256), 0, stream,
                     eidx, prob, hidden, hidden_b, wi, wi_t, wo, wo_t, nxt,
                     pair_token, pair_pos, pair_coef, seg_off, seg_cnt);
  // 2) GEMM1: act = relu(hidden @ wi[e]); K=512, N=2048 (R6-verbatim launch)
  hipLaunchKernelGGL((gemm_kernel<DM, true, true>), dim3(16, 64, NE), dim3(256), 0, stream,
                     hidden_b, wi_t, pair_token, (const float*)nullptr, seg_off, seg_cnt,
                     act, (float*)nullptr, DF, 15, 4, DM);
  // 3) GEMM2: next[token] += coef * (act @ wo[e]); K=2048, split 4, atomic f32
  hipLaunchKernelGGL((gemm_kernel<DF, false, false>), dim3(4 * SPLIT, 64, NE), dim3(256), 0, stream,
                     act, wo_t, pair_token, pair_coef, seg_off, seg_cnt,
                     (u16*)nullptr, nxt, DM, 3, 2, DF / SPLIT);
  // 4) combine: out = where(next != 0, next, hidden)
  hipLaunchKernelGGL(combine_kernel, dim3(2048), dim3(256), 0, stream,
                     hidden, nxt, out);
}

// Round 8
// 231.038 us; speedup vs baseline: 1.1156x; 1.1156x over previous
//
#include <hip/hip_runtime.h>
#include <cstdint>
#include <cstddef>

#define TOKENS 4096
#define DM 512
#define DF 2048
#define NE 8
#define NPAIR 8192  // TOKENS * TOPK
#define SPLIT 2     // split-K factor for GEMM2 (f32 partials, R6-proven reduction)

typedef unsigned short u16;
typedef __attribute__((ext_vector_type(8))) short short8;
typedef __attribute__((ext_vector_type(4))) float f32x4;

// fp32 -> bf16 round-to-nearest-even (finite inputs only)
__device__ __forceinline__ u16 f2b(float x) {
  uint32_t u = __builtin_bit_cast(uint32_t, x);
  uint32_t r = (u + 0x7fffu + ((u >> 16) & 1u)) >> 16;
  return (u16)r;
}

__device__ __forceinline__ void gl_lds16(const void* gsrc, void* ldst) {
  __builtin_amdgcn_global_load_lds(
      (__attribute__((address_space(1))) void*)(gsrc),
      (__attribute__((address_space(3))) void*)(ldst), 16, 0, 0);
}

// ---------------- prep: one dispatch, four R6-verbatim (proven) bodies ----------------
// bid 0            : routing
// bid 1..2048      : hidden fp32 -> bf16
// bid 2049..4096   : tr wi  [8][512][2048] -> [8][2048][512]
// bid 4097..6144   : tr wo  [8][2048][512] -> [8][512][2048]
__global__ __launch_bounds__(256) void prep_kernel(
    const int* __restrict__ eidx, const float* __restrict__ hidden, u16* __restrict__ hidden_b,
    const float* __restrict__ wi, u16* __restrict__ wi_t,
    const float* __restrict__ wo, u16* __restrict__ wo_t,
    int* __restrict__ pair_token, int* __restrict__ pair_pos,
    int* __restrict__ seg_off, int* __restrict__ seg_cnt) {
  __shared__ __align__(16) float t[64][65];
  int bid = blockIdx.x;
  int tid = threadIdx.x;
  if (bid == 0) {
    int* cnt = (int*)&t[0][0];
    int* off = cnt + 8;
    int* cur = cnt + 16;
    if (tid < NE) { cnt[tid] = 0; cur[tid] = 0; }
    __syncthreads();
    for (int i = tid; i < NPAIR; i += 256) atomicAdd(&cnt[eidx[i]], 1);
    __syncthreads();
    if (tid == 0) {
      int a = 0;
      for (int e = 0; e < NE; ++e) { off[e] = a; a += cnt[e]; }
    }
    __syncthreads();
    for (int i = tid; i < NPAIR; i += 256) {
      int e = eidx[i];
      int p = off[e] + atomicAdd(&cur[e], 1);
      pair_token[p] = i >> 1;  // token index
      pair_pos[i] = p;         // where this (token,k) landed
    }
    if (tid < NE) { seg_off[tid] = off[tid]; seg_cnt[tid] = cnt[tid]; }
  } else if (bid <= 2048) {
    int i = (bid - 1) * 256 + tid;  // float4 group
    float4 v = ((const float4*)hidden)[i];
    ushort4 o;
    o.x = f2b(v.x); o.y = f2b(v.y); o.z = f2b(v.z); o.w = f2b(v.w);
    ((ushort4*)hidden_b)[i] = o;
  } else if (bid <= 4096) {
    const int R = DM, C = DF;
    int f = bid - 2049;
    int e = f >> 8;
    int cb = (f & 31) * 64, rb = ((f >> 5) & 7) * 64;
    const float* s = wi + (size_t)e * R * C;
    u16* d = wi_t + (size_t)e * R * C;
    int r = tid >> 4, cq = tid & 15;
#pragma unroll
    for (int i = 0; i < 4; ++i) {
      float4 v = *(const float4*)&s[(size_t)(rb + r + 16 * i) * C + cb + cq * 4];
      t[r + 16 * i][cq * 4 + 0] = v.x;
      t[r + 16 * i][cq * 4 + 1] = v.y;
      t[r + 16 * i][cq * 4 + 2] = v.z;
      t[r + 16 * i][cq * 4 + 3] = v.w;
    }
    __syncthreads();
    int rq = tid & 15, c0 = tid >> 4;
#pragma unroll
    for (int i = 0; i < 4; ++i) {
      int c = c0 + 16 * i;
      ushort4 o;
      o.x = f2b(t[rq * 4 + 0][c]);
      o.y = f2b(t[rq * 4 + 1][c]);
      o.z = f2b(t[rq * 4 + 2][c]);
      o.w = f2b(t[rq * 4 + 3][c]);
      *(ushort4*)&d[(size_t)(cb + c) * R + rb + rq * 4] = o;
    }
  } else {
    const int R = DF, C = DM;
    int f = bid - 4097;
    int e = f >> 8;
    int cb = (f & 7) * 64, rb = ((f >> 3) & 31) * 64;
    const float* s = wo + (size_t)e * R * C;
    u16* d = wo_t + (size_t)e * R * C;
    int r = tid >> 4, cq = tid & 15;
#pragma unroll
    for (int i = 0; i < 4; ++i) {
      float4 v = *(const float4*)&s[(size_t)(rb + r + 16 * i) * C + cb + cq * 4];
      t[r + 16 * i][cq * 4 + 0] = v.x;
      t[r + 16 * i][cq * 4 + 1] = v.y;
      t[r + 16 * i][cq * 4 + 2] = v.z;
      t[r + 16 * i][cq * 4 + 3] = v.w;
    }
    __syncthreads();
    int rq = tid & 15, c0 = tid >> 4;
#pragma unroll
    for (int i = 0; i < 4; ++i) {
      int c = c0 + 16 * i;
      ushort4 o;
      o.x = f2b(t[rq * 4 + 0][c]);
      o.y = f2b(t[rq * 4 + 1][c]);
      o.z = f2b(t[rq * 4 + 2][c]);
      o.w = f2b(t[rq * 4 + 3][c]);
      *(ushort4*)&d[(size_t)(cb + c) * R + rb + rq * 4] = o;
    }
  }
}

// ---------------- 1-wave grouped GEMM, 64x64 tile, barrier-free pipelined K-loop ----
// C[m][n] = sum_{k in [sp*ks, +ks)} A[row(m)][k] * Bt[n][k]; BK=32, double-buffered
// LDS with explicit s_waitcnt (no __syncthreads: single wave per block).
// blockIdx = (x = (sp << sp_shift) | nt, y = mt, z = e).
template <int KDIM, bool GATHER, bool RELU>
__global__ __launch_bounds__(64) void gemm64_kernel(
    const u16* __restrict__ A,         // [*, KDIM] bf16 rows
    const u16* __restrict__ Bt,        // [NE][n_total][KDIM] bf16
    const int* __restrict__ pair_token,
    const int* __restrict__ seg_off, const int* __restrict__ seg_cnt,
    u16* __restrict__ out_b,           // act (RELU)
    float* __restrict__ out_f,         // Ypart (!RELU)
    int n_total, int nt_mask, int sp_shift, int ks) {
  const int e = blockIdx.z;
  const int cnt = seg_cnt[e];
  const int mt = blockIdx.y;
  if (mt * 64 >= cnt) return;
  const int off = seg_off[e];
  const int nt = blockIdx.x & nt_mask;
  const int sp = blockIdx.x >> sp_shift;
  const int kb = sp * ks;
  const int lane = threadIdx.x;  // 0..63, one wave

  // double-buffered tiles: [buf][64 rows][32 k] bf16 (4 KB each) -> 16 KB total
  __shared__ __align__(16) u16 Al[2][64 * 32];
  __shared__ __align__(16) u16 Bl[2][64 * 32];

  // staging: instr g covers rows [g*16, +16); lane -> row g*16 + lane/4,
  // 16B chunk lane%4 (8 bf16). LDS dst = wave-uniform base (+ lane*16 implicit).
  const int rr = lane >> 2;
  const int cc = (lane & 3) * 8;

  const u16* aSrc[4];
  const u16* bSrc[4];
  const u16* BtBase = Bt + ((size_t)e * n_total + (size_t)nt * 64) * KDIM;
#pragma unroll
  for (int g = 0; g < 4; ++g) {
    int rl = g * 16 + rr;
    int m = mt * 64 + rl;
    if (m > cnt - 1) m = cnt - 1;  // clamp padding rows to valid data
    int srow = GATHER ? pair_token[off + m] : (off + m);
    aSrc[g] = A + (size_t)srow * KDIM + cc;
    bSrc[g] = BtBase + (size_t)rl * KDIM + cc;
  }

  const int rl16 = lane & 15;
  const int kk = (lane >> 4) * 8;

  f32x4 acc[4][4];
#pragma unroll
  for (int i = 0; i < 4; ++i)
#pragma unroll
    for (int j = 0; j < 4; ++j)
#pragma unroll
      for (int r = 0; r < 4; ++r) acc[i][j][r] = 0.0f;

  const int niter = ks >> 5;  // BK=32

  // prologue: fill buffer 0 (8 loads in flight)
#pragma unroll
  for (int g = 0; g < 4; ++g) {
    gl_lds16(aSrc[g] + kb, &Al[0][g * 16 * 32]);
    gl_lds16(bSrc[g] + kb, &Bl[0][g * 16 * 32]);
  }

  for (int i = 0; i < niter; ++i) {
    const int cur = i & 1;
    // WAR: frag ds_reads of iter i-1 (targeting buf cur^1) must complete
    // before we overwrite that buffer.
    asm volatile("s_waitcnt lgkmcnt(0)" ::: "memory");
    if (i + 1 < niter) {
      const int nxt = cur ^ 1;
      const int k1 = kb + ((i + 1) << 5);
#pragma unroll
      for (int g = 0; g < 4; ++g) {
        gl_lds16(aSrc[g] + k1, &Al[nxt][g * 16 * 32]);
        gl_lds16(bSrc[g] + k1, &Bl[nxt][g * 16 * 32]);
      }
      // 16 outstanding; wait until only next-buffer's 8 remain -> cur buf landed
      asm volatile("s_waitcnt vmcnt(8)" ::: "memory");
    } else {
      asm volatile("s_waitcnt vmcnt(0)" ::: "memory");
    }
    short8 af[4], bf[4];
#pragma unroll
    for (int mi = 0; mi < 4; ++mi)
      af[mi] = *(const short8*)&Al[cur][(mi * 16 + rl16) * 32 + kk];
#pragma unroll
    for (int ni = 0; ni < 4; ++ni)
      bf[ni] = *(const short8*)&Bl[cur][(ni * 16 + rl16) * 32 + kk];
#pragma unroll
    for (int mi = 0; mi < 4; ++mi)
#pragma unroll
      for (int ni = 0; ni < 4; ++ni)
        acc[mi][ni] = __builtin_amdgcn_mfma_f32_16x16x32_bf16(af[mi], bf[ni], acc[mi][ni], 0, 0, 0);
  }

  // epilogue: D[row][col]: col = lane&15, row = (lane>>4)*4 + reg
  float* outp = RELU ? nullptr : (out_f + (size_t)sp * NPAIR * DM);
  const int rowq = (lane >> 4) * 4;
#pragma unroll
  for (int mi = 0; mi < 4; ++mi) {
#pragma unroll
    for (int r = 0; r < 4; ++r) {
      int m = mt * 64 + mi * 16 + rowq + r;
      if (m < cnt) {
        size_t rowp = (size_t)(off + m) * n_total;
#pragma unroll
        for (int ni = 0; ni < 4; ++ni) {
          int n = nt * 64 + ni * 16 + rl16;
          float v = acc[mi][ni][r];
          if (RELU) {
            v = v > 0.0f ? v : 0.0f;
            out_b[rowp + n] = f2b(v);
          } else {
            outp[rowp + n] = v;
          }
        }
      }
    }
  }
}

// ---------------- combine (R6-verbatim, f32 partials) ----------------
__global__ void combine_kernel(const float* __restrict__ hidden,
                               const float* __restrict__ prob,
                               const int* __restrict__ pair_pos,
                               const float* __restrict__ Ypart,
                               float* __restrict__ out, int nsplit) {
  int i = blockIdx.x * 256 + threadIdx.x;  // group of 4 floats
  int t = i >> 7;                          // 128 groups per token (512/4)
  int g = i & 127;
  int p0 = pair_pos[2 * t], p1 = pair_pos[2 * t + 1];
  float c0 = 0.5f * prob[2 * t];
  float c1 = 0.25f * prob[2 * t + 1];
  float4 a = {0.f, 0.f, 0.f, 0.f}, b = {0.f, 0.f, 0.f, 0.f};
  for (int s = 0; s < nsplit; ++s) {
    const float4* Y = (const float4*)(Ypart + (size_t)s * NPAIR * DM);
    float4 va = Y[(size_t)p0 * 128 + g];
    float4 vb = Y[(size_t)p1 * 128 + g];
    a.x += va.x; a.y += va.y; a.z += va.z; a.w += va.w;
    b.x += vb.x; b.y += vb.y; b.z += vb.z; b.w += vb.w;
  }
  float4 h = ((const float4*)hidden)[i];
  float4 r, o;
  r.x = c0 * a.x + c1 * b.x;
  r.y = c0 * a.y + c1 * b.y;
  r.z = c0 * a.z + c1 * b.z;
  r.w = c0 * a.w + c1 * b.w;
  o.x = (r.x != 0.0f) ? r.x : h.x;
  o.y = (r.y != 0.0f) ? r.y : h.y;
  o.z = (r.z != 0.0f) ? r.z : h.z;
  o.w = (r.w != 0.0f) ? r.w : h.w;
  ((float4*)out)[i] = o;
}

extern "C" void kernel_launch(void* const* d_in, const int* in_sizes, int n_in,
                              void* d_out, int out_size, void* d_ws, size_t ws_size,
                              hipStream_t stream) {
  const float* hidden = (const float*)d_in[0];
  const float* prob = (const float*)d_in[1];
  const float* wi = (const float*)d_in[2];
  const float* wo = (const float*)d_in[3];
  const int* eidx = (const int*)d_in[4];
  float* out = (float*)d_out;

  char* ws = (char*)d_ws;
  u16* hidden_b = (u16*)(ws + 0);                     //  4 MB [4096][512] bf16
  u16* wi_t = (u16*)(ws + ((size_t)4 << 20));         // 16 MB [8][2048][512] bf16 (wi^T)
  u16* wo_t = (u16*)(ws + ((size_t)20 << 20));        // 16 MB [8][512][2048] bf16 (wo^T)
  u16* act = (u16*)(ws + ((size_t)36 << 20));         // 32 MB [8192][2048] bf16
  float* Ypart = (float*)(ws + ((size_t)68 << 20));   // 32 MB [2][8192][512] f32
  char* smalls = ws + ((size_t)132 << 20);            // proven offset
  int* pair_token = (int*)(smalls);
  int* pair_pos = (int*)(smalls + (64u << 10));
  int* seg_off = (int*)(smalls + (128u << 10));
  int* seg_cnt = (int*)(smalls + (128u << 10) + 256);

  // 1) prep: routing | hidden cvt | tr wi | tr wo (R6-verbatim)
  hipLaunchKernelGGL(prep_kernel, dim3(6145), dim3(256), 0, stream,
                     eidx, hidden, hidden_b, wi, wi_t, wo, wo_t,
                     pair_token, pair_pos, seg_off, seg_cnt);
  // 2) GEMM1: act = relu(hidden @ wi[e]); K=512, N=2048 (32 nt), 64x64 tiles.
  //    y=40 covers per-expert cnt up to 2560 (fixed-seed counts are ~1024±60).
  hipLaunchKernelGGL((gemm64_kernel<DM, true, true>), dim3(32, 40, NE), dim3(64), 0, stream,
                     hidden_b, wi_t, pair_token, seg_off, seg_cnt,
                     act, (float*)nullptr, DF, 31, 5, DM);
  // 3) GEMM2: Ypart[sp] = act @ wo[e]; K=2048 split 2, N=512 (8 nt), 64x64 tiles
  hipLaunchKernelGGL((gemm64_kernel<DF, false, false>), dim3(8 * SPLIT, 40, NE), dim3(64), 0, stream,
                     act, wo_t, (const int*)nullptr, seg_off, seg_cnt,
                     (u16*)nullptr, Ypart, DM, 7, 3, DF / SPLIT);
  // 4) combine + where(next!=0, next, hidden) (R6-verbatim, nsplit=2)
  hipLaunchKernelGGL(combine_kernel, dim3(2048), dim3(256), 0, stream,
                     hidden, prob, pair_pos, Ypart, out, SPLIT);
}

// Round 9
// 224.076 us; speedup vs baseline: 1.1502x; 1.0311x over previous
//
#include <hip/hip_runtime.h>
#include <cstdint>
#include <cstddef>

#define TOKENS 4096
#define DM 512
#define DF 2048
#define NE 8
#define NPAIR 8192  // TOKENS * TOPK
#define SPLIT 4     // split-K factor for GEMM2 (f32 partials, R6-proven)

typedef unsigned short u16;
typedef __attribute__((ext_vector_type(8))) short short8;
typedef __attribute__((ext_vector_type(4))) float f32x4;

// fp32 -> bf16 round-to-nearest-even (finite inputs only)
__device__ __forceinline__ u16 f2b(float x) {
  uint32_t u = __builtin_bit_cast(uint32_t, x);
  uint32_t r = (u + 0x7fffu + ((u >> 16) & 1u)) >> 16;
  return (u16)r;
}

__device__ __forceinline__ void gl_lds16(const void* gsrc, void* ldst) {
  __builtin_amdgcn_global_load_lds(
      (__attribute__((address_space(1))) void*)(gsrc),
      (__attribute__((address_space(3))) void*)(ldst), 16, 0, 0);
}

// ---------------- prep: one dispatch, R6-verbatim bodies + tile-list build ----------------
// bid 0            : routing + compact (expert, m-tile) list
// bid 1..2048      : hidden fp32 -> bf16
// bid 2049..4096   : tr wi  [8][512][2048] -> [8][2048][512]
// bid 4097..6144   : tr wo  [8][2048][512] -> [8][512][2048]
__global__ __launch_bounds__(256) void prep_kernel(
    const int* __restrict__ eidx, const float* __restrict__ hidden, u16* __restrict__ hidden_b,
    const float* __restrict__ wi, u16* __restrict__ wi_t,
    const float* __restrict__ wo, u16* __restrict__ wo_t,
    int* __restrict__ pair_token, int* __restrict__ pair_pos,
    int* __restrict__ seg_off, int* __restrict__ seg_cnt,
    int* __restrict__ tl_e, int* __restrict__ tl_mt) {
  __shared__ __align__(16) float t[64][65];
  int bid = blockIdx.x;
  int tid = threadIdx.x;
  if (bid == 0) {
    int* cnt = (int*)&t[0][0];
    int* off = cnt + 8;
    int* cur = cnt + 16;
    if (tid < NE) { cnt[tid] = 0; cur[tid] = 0; }
    __syncthreads();
    for (int i = tid; i < NPAIR; i += 256) atomicAdd(&cnt[eidx[i]], 1);
    __syncthreads();
    if (tid == 0) {
      int a = 0;
      for (int e = 0; e < NE; ++e) { off[e] = a; a += cnt[e]; }
      // compact (expert, m-tile) list; sum ceil(cnt/128) <= 71 always
      int n = 0;
      for (int e = 0; e < NE; ++e) {
        int ntl = (cnt[e] + 127) >> 7;
        for (int m = 0; m < ntl && n < 128; ++m, ++n) { tl_e[n] = e; tl_mt[n] = m; }
      }
      for (; n < 128; ++n) { tl_e[n] = -1; tl_mt[n] = 0; }
    }
    __syncthreads();
    for (int i = tid; i < NPAIR; i += 256) {
      int e = eidx[i];
      int p = off[e] + atomicAdd(&cur[e], 1);
      pair_token[p] = i >> 1;  // token index
      pair_pos[i] = p;         // where this (token,k) landed
    }
    if (tid < NE) { seg_off[tid] = off[tid]; seg_cnt[tid] = cnt[tid]; }
  } else if (bid <= 2048) {
    int i = (bid - 1) * 256 + tid;  // float4 group
    float4 v = ((const float4*)hidden)[i];
    ushort4 o;
    o.x = f2b(v.x); o.y = f2b(v.y); o.z = f2b(v.z); o.w = f2b(v.w);
    ((ushort4*)hidden_b)[i] = o;
  } else if (bid <= 4096) {
    const int R = DM, C = DF;
    int f = bid - 2049;
    int e = f >> 8;
    int cb = (f & 31) * 64, rb = ((f >> 5) & 7) * 64;
    const float* s = wi + (size_t)e * R * C;
    u16* d = wi_t + (size_t)e * R * C;
    int r = tid >> 4, cq = tid & 15;
#pragma unroll
    for (int i = 0; i < 4; ++i) {
      float4 v = *(const float4*)&s[(size_t)(rb + r + 16 * i) * C + cb + cq * 4];
      t[r + 16 * i][cq * 4 + 0] = v.x;
      t[r + 16 * i][cq * 4 + 1] = v.y;
      t[r + 16 * i][cq * 4 + 2] = v.z;
      t[r + 16 * i][cq * 4 + 3] = v.w;
    }
    __syncthreads();
    int rq = tid & 15, c0 = tid >> 4;
#pragma unroll
    for (int i = 0; i < 4; ++i) {
      int c = c0 + 16 * i;
      ushort4 o;
      o.x = f2b(t[rq * 4 + 0][c]);
      o.y = f2b(t[rq * 4 + 1][c]);
      o.z = f2b(t[rq * 4 + 2][c]);
      o.w = f2b(t[rq * 4 + 3][c]);
      *(ushort4*)&d[(size_t)(cb + c) * R + rb + rq * 4] = o;
    }
  } else {
    const int R = DF, C = DM;
    int f = bid - 4097;
    int e = f >> 8;
    int cb = (f & 7) * 64, rb = ((f >> 3) & 31) * 64;
    const float* s = wo + (size_t)e * R * C;
    u16* d = wo_t + (size_t)e * R * C;
    int r = tid >> 4, cq = tid & 15;
#pragma unroll
    for (int i = 0; i < 4; ++i) {
      float4 v = *(const float4*)&s[(size_t)(rb + r + 16 * i) * C + cb + cq * 4];
      t[r + 16 * i][cq * 4 + 0] = v.x;
      t[r + 16 * i][cq * 4 + 1] = v.y;
      t[r + 16 * i][cq * 4 + 2] = v.z;
      t[r + 16 * i][cq * 4 + 3] = v.w;
    }
    __syncthreads();
    int rq = tid & 15, c0 = tid >> 4;
#pragma unroll
    for (int i = 0; i < 4; ++i) {
      int c = c0 + 16 * i;
      ushort4 o;
      o.x = f2b(t[rq * 4 + 0][c]);
      o.y = f2b(t[rq * 4 + 1][c]);
      o.z = f2b(t[rq * 4 + 2][c]);
      o.w = f2b(t[rq * 4 + 3][c]);
      *(ushort4*)&d[(size_t)(cb + c) * R + rb + rq * 4] = o;
    }
  }
}

// ---------------- grouped GEMM, R6-verbatim body, tile-list driven ----------------
// C[m][n] = sum_{k in [sp*ks, +ks)} A[row(m)][k] * Bt[n][k]; tile 128x128, 4 waves.
// blockIdx.x = (sp << sp_shift) | nt; (e, mt) = tile list [blockIdx.y].
template <int KDIM, bool GATHER, bool RELU_BF16>
__global__ __launch_bounds__(256) void gemm_kernel(
    const u16* __restrict__ A,         // [*, KDIM] bf16 rows
    const u16* __restrict__ Bt,        // [NE][n_total][KDIM] bf16
    const int* __restrict__ pair_token,
    const int* __restrict__ seg_off, const int* __restrict__ seg_cnt,
    const int* __restrict__ tl_e, const int* __restrict__ tl_mt,
    u16* __restrict__ out_b,           // act (RELU_BF16)
    float* __restrict__ out_f,         // Ypart (!RELU_BF16)
    int n_total, int nt_mask, int sp_shift, int ks) {
  const int e = tl_e[blockIdx.y];
  if (e < 0) return;
  const int mt = tl_mt[blockIdx.y];
  const int cnt = seg_cnt[e];
  const int off = seg_off[e];
  const int nt = blockIdx.x & nt_mask;
  const int sp = blockIdx.x >> sp_shift;
  const int kb = sp * ks, ke = kb + ks;
  const int tid = threadIdx.x;
  const int wave = tid >> 6, lane = tid & 63;

  __shared__ __align__(16) u16 Al[128 * 32];
  __shared__ __align__(16) u16 Bl[128 * 32];

  const int r0 = wave * 32;
  const int rr = lane >> 2;
  const int cc = (lane & 3) * 8;  // element offset (8 bf16 = 16B)

  const u16* aSrc[2];
  const u16* bSrc[2];
  const u16* BtBase = Bt + ((size_t)e * n_total + (size_t)nt * 128) * KDIM;
#pragma unroll
  for (int g = 0; g < 2; ++g) {
    int rl = r0 + g * 16 + rr;
    int m = mt * 128 + rl;
    if (m > cnt - 1) m = cnt - 1;  // clamp padding rows to valid data
    int srow = GATHER ? pair_token[off + m] : (off + m);
    aSrc[g] = A + (size_t)srow * KDIM + cc;
    bSrc[g] = BtBase + (size_t)rl * KDIM + cc;
  }

  const int wm = wave >> 1, wn = wave & 1;
  const int rl16 = lane & 15;
  const int kk = (lane >> 4) * 8;

  f32x4 acc[4][4];
#pragma unroll
  for (int i = 0; i < 4; ++i)
#pragma unroll
    for (int j = 0; j < 4; ++j)
#pragma unroll
      for (int r = 0; r < 4; ++r) acc[i][j][r] = 0.0f;

  for (int k0 = kb; k0 < ke; k0 += 32) {
#pragma unroll
    for (int g = 0; g < 2; ++g) {
      gl_lds16(aSrc[g] + k0, &Al[(r0 + g * 16) * 32]);
      gl_lds16(bSrc[g] + k0, &Bl[(r0 + g * 16) * 32]);
    }
    __syncthreads();
    short8 af[4], bf[4];
#pragma unroll
    for (int mi = 0; mi < 4; ++mi)
      af[mi] = *(const short8*)&Al[(wm * 64 + mi * 16 + rl16) * 32 + kk];
#pragma unroll
    for (int ni = 0; ni < 4; ++ni)
      bf[ni] = *(const short8*)&Bl[(wn * 64 + ni * 16 + rl16) * 32 + kk];
#pragma unroll
    for (int mi = 0; mi < 4; ++mi)
#pragma unroll
      for (int ni = 0; ni < 4; ++ni)
        acc[mi][ni] = __builtin_amdgcn_mfma_f32_16x16x32_bf16(af[mi], bf[ni], acc[mi][ni], 0, 0, 0);
    __syncthreads();
  }

  float* outp = RELU_BF16 ? nullptr : (out_f + (size_t)sp * NPAIR * DM);

  // epilogue: D[row][col]: col = lane&15, row = (lane>>4)*4 + reg
  const int rowq = (lane >> 4) * 4;
#pragma unroll
  for (int mi = 0; mi < 4; ++mi) {
#pragma unroll
    for (int r = 0; r < 4; ++r) {
      int m = mt * 128 + wm * 64 + mi * 16 + rowq + r;
      if (m < cnt) {
        size_t rowp = (size_t)(off + m) * n_total;
#pragma unroll
        for (int ni = 0; ni < 4; ++ni) {
          int n = nt * 128 + wn * 64 + ni * 16 + rl16;
          float v = acc[mi][ni][r];
          if (RELU_BF16) {
            v = v > 0.0f ? v : 0.0f;
            out_b[rowp + n] = f2b(v);
          } else {
            outp[rowp + n] = v;
          }
        }
      }
    }
  }
}

// ---------------- combine (R6-verbatim, f32 partials) ----------------
__global__ void combine_kernel(const float* __restrict__ hidden,
                               const float* __restrict__ prob,
                               const int* __restrict__ pair_pos,
                               const float* __restrict__ Ypart,
                               float* __restrict__ out, int nsplit) {
  int i = blockIdx.x * 256 + threadIdx.x;  // group of 4 floats
  int t = i >> 7;                          // 128 groups per token (512/4)
  int g = i & 127;
  int p0 = pair_pos[2 * t], p1 = pair_pos[2 * t + 1];
  float c0 = 0.5f * prob[2 * t];
  float c1 = 0.25f * prob[2 * t + 1];
  float4 a = {0.f, 0.f, 0.f, 0.f}, b = {0.f, 0.f, 0.f, 0.f};
  for (int s = 0; s < nsplit; ++s) {
    const float4* Y = (const float4*)(Ypart + (size_t)s * NPAIR * DM);
    float4 va = Y[(size_t)p0 * 128 + g];
    float4 vb = Y[(size_t)p1 * 128 + g];
    a.x += va.x; a.y += va.y; a.z += va.z; a.w += va.w;
    b.x += vb.x; b.y += vb.y; b.z += vb.z; b.w += vb.w;
  }
  float4 h = ((const float4*)hidden)[i];
  float4 r, o;
  r.x = c0 * a.x + c1 * b.x;
  r.y = c0 * a.y + c1 * b.y;
  r.z = c0 * a.z + c1 * b.z;
  r.w = c0 * a.w + c1 * b.w;
  o.x = (r.x != 0.0f) ? r.x : h.x;
  o.y = (r.y != 0.0f) ? r.y : h.y;
  o.z = (r.z != 0.0f) ? r.z : h.z;
  o.w = (r.w != 0.0f) ? r.w : h.w;
  ((float4*)out)[i] = o;
}

extern "C" void kernel_launch(void* const* d_in, const int* in_sizes, int n_in,
                              void* d_out, int out_size, void* d_ws, size_t ws_size,
                              hipStream_t stream) {
  const float* hidden = (const float*)d_in[0];
  const float* prob = (const float*)d_in[1];
  const float* wi = (const float*)d_in[2];
  const float* wo = (const float*)d_in[3];
  const int* eidx = (const int*)d_in[4];
  float* out = (float*)d_out;

  // R6-proven workspace layout (split=4, f32 partials)
  char* ws = (char*)d_ws;
  u16* hidden_b = (u16*)(ws + 0);                     //  4 MB [4096][512] bf16
  u16* wi_t = (u16*)(ws + ((size_t)4 << 20));         // 16 MB [8][2048][512] bf16 (wi^T)
  u16* wo_t = (u16*)(ws + ((size_t)20 << 20));        // 16 MB [8][512][2048] bf16 (wo^T)
  u16* act = (u16*)(ws + ((size_t)36 << 20));         // 32 MB [8192][2048] bf16
  float* Ypart = (float*)(ws + ((size_t)68 << 20));   // 64 MB [4][8192][512] f32
  char* smalls = ws + ((size_t)132 << 20);
  int* pair_token = (int*)(smalls);
  int* pair_pos = (int*)(smalls + (64u << 10));
  int* seg_off = (int*)(smalls + (128u << 10));
  int* seg_cnt = (int*)(smalls + (128u << 10) + 256);
  int* tl_e = (int*)(smalls + (129u << 10));          // 128 ints
  int* tl_mt = (int*)(smalls + (129u << 10) + 512);   // 128 ints

  // 1) prep: routing+tilelist | hidden cvt | tr wi | tr wo — one dispatch
  hipLaunchKernelGGL(prep_kernel, dim3(6145), dim3(256), 0, stream,
                     eidx, hidden, hidden_b, wi, wi_t, wo, wo_t,
                     pair_token, pair_pos, seg_off, seg_cnt, tl_e, tl_mt);
  // 2) GEMM1: act = relu(hidden @ wi[e]); K=512, N=2048; dense tile list (y=72)
  hipLaunchKernelGGL((gemm_kernel<DM, true, true>), dim3(16, 72, 1), dim3(256), 0, stream,
                     hidden_b, wi_t, pair_token, seg_off, seg_cnt, tl_e, tl_mt,
                     act, (float*)nullptr, DF, 15, 4, DM);
  // 3) GEMM2: Ypart[sp] = act @ wo[e] (f32 partials); K=2048 split 4; dense tiles
  hipLaunchKernelGGL((gemm_kernel<DF, false, false>), dim3(4 * SPLIT, 72, 1), dim3(256), 0, stream,
                     act, wo_t, (const int*)nullptr, seg_off, seg_cnt, tl_e, tl_mt,
                     (u16*)nullptr, Ypart, DM, 3, 2, DF / SPLIT);
  // 4) combine + where(next!=0, next, hidden) (R6-verbatim)
  hipLaunchKernelGGL(combine_kernel, dim3(2048), dim3(256), 0, stream,
                     hidden, prob, pair_pos, Ypart, out, SPLIT);
}

// Round 10
// 219.863 us; speedup vs baseline: 1.1723x; 1.0192x over previous
//
#include <hip/hip_runtime.h>
#include <cstdint>
#include <cstddef>

#define TOKENS 4096
#define DM 512
#define DF 2048
#define NE 8
#define NPAIR 8192  // TOKENS * TOPK
#define SPLIT 4     // split-K factor for GEMM2 (f32 partials, proven)

typedef unsigned short u16;
typedef __attribute__((ext_vector_type(8))) short short8;
typedef __attribute__((ext_vector_type(4))) float f32x4;

// fp32 -> bf16 round-to-nearest-even (finite inputs only)
__device__ __forceinline__ u16 f2b(float x) {
  uint32_t u = __builtin_bit_cast(uint32_t, x);
  uint32_t r = (u + 0x7fffu + ((u >> 16) & 1u)) >> 16;
  return (u16)r;
}

__device__ __forceinline__ void gl_lds16(const void* gsrc, void* ldst) {
  __builtin_amdgcn_global_load_lds(
      (__attribute__((address_space(1))) void*)(gsrc),
      (__attribute__((address_space(3))) void*)(ldst), 16, 0, 0);
}

// ---------------- prep: routing+tilelist | hidden cvt | tr wi (wo moved to GEMM1) ----
// bid 0            : routing + compact (expert, m-tile) list
// bid 1..2048      : hidden fp32 -> bf16
// bid 2049..4096   : tr wi  [8][512][2048] -> [8][2048][512]
__global__ __launch_bounds__(256) void prep_kernel(
    const int* __restrict__ eidx, const float* __restrict__ hidden, u16* __restrict__ hidden_b,
    const float* __restrict__ wi, u16* __restrict__ wi_t,
    int* __restrict__ pair_token, int* __restrict__ pair_pos,
    int* __restrict__ seg_off, int* __restrict__ seg_cnt,
    int* __restrict__ tl_e, int* __restrict__ tl_mt) {
  __shared__ __align__(16) float t[64][65];
  int bid = blockIdx.x;
  int tid = threadIdx.x;
  if (bid == 0) {
    int* cnt = (int*)&t[0][0];
    int* off = cnt + 8;
    int* cur = cnt + 16;
    if (tid < NE) { cnt[tid] = 0; cur[tid] = 0; }
    __syncthreads();
    for (int i = tid; i < NPAIR; i += 256) atomicAdd(&cnt[eidx[i]], 1);
    __syncthreads();
    if (tid == 0) {
      int a = 0;
      for (int e = 0; e < NE; ++e) { off[e] = a; a += cnt[e]; }
      // compact (expert, m-tile) list; sum ceil(cnt/128) <= 71 always
      int n = 0;
      for (int e = 0; e < NE; ++e) {
        int ntl = (cnt[e] + 127) >> 7;
        for (int m = 0; m < ntl && n < 128; ++m, ++n) { tl_e[n] = e; tl_mt[n] = m; }
      }
      for (; n < 128; ++n) { tl_e[n] = -1; tl_mt[n] = 0; }
    }
    __syncthreads();
    for (int i = tid; i < NPAIR; i += 256) {
      int e = eidx[i];
      int p = off[e] + atomicAdd(&cur[e], 1);
      pair_token[p] = i >> 1;  // token index
      pair_pos[i] = p;         // where this (token,k) landed
    }
    if (tid < NE) { seg_off[tid] = off[tid]; seg_cnt[tid] = cnt[tid]; }
  } else if (bid <= 2048) {
    int i = (bid - 1) * 256 + tid;  // float4 group
    float4 v = ((const float4*)hidden)[i];
    ushort4 o;
    o.x = f2b(v.x); o.y = f2b(v.y); o.z = f2b(v.z); o.w = f2b(v.w);
    ((ushort4*)hidden_b)[i] = o;
  } else {
    const int R = DM, C = DF;
    int f = bid - 2049;
    int e = f >> 8;
    int cb = (f & 31) * 64, rb = ((f >> 5) & 7) * 64;
    const float* s = wi + (size_t)e * R * C;
    u16* d = wi_t + (size_t)e * R * C;
    int r = tid >> 4, cq = tid & 15;
#pragma unroll
    for (int i = 0; i < 4; ++i) {
      float4 v = *(const float4*)&s[(size_t)(rb + r + 16 * i) * C + cb + cq * 4];
      t[r + 16 * i][cq * 4 + 0] = v.x;
      t[r + 16 * i][cq * 4 + 1] = v.y;
      t[r + 16 * i][cq * 4 + 2] = v.z;
      t[r + 16 * i][cq * 4 + 3] = v.w;
    }
    __syncthreads();
    int rq = tid & 15, c0 = tid >> 4;
#pragma unroll
    for (int i = 0; i < 4; ++i) {
      int c = c0 + 16 * i;
      ushort4 o;
      o.x = f2b(t[rq * 4 + 0][c]);
      o.y = f2b(t[rq * 4 + 1][c]);
      o.z = f2b(t[rq * 4 + 2][c]);
      o.w = f2b(t[rq * 4 + 3][c]);
      *(ushort4*)&d[(size_t)(cb + c) * R + rb + rq * 4] = o;
    }
  }
}

// ---------------- grouped GEMM (R9-proven body), optional fused tr_wo z-planes ----
// z == 0: C[m][n] = sum_{k in [sp*ks, +ks)} A[row(m)][k] * Bt[n][k]; 128x128, 4 waves.
//         blockIdx.x = (sp << sp_shift) | nt; (e, mt) = tile list [blockIdx.y].
// z >= 1 (FUSE_TR): 2048 tr tiles for wo [8][2048][512] -> wo_t [8][512][2048];
//         flat = (z-1)*1152 + y*16 + x; bx=flat&7, by=(flat>>3)&31, e=flat>>8.
template <int KDIM, bool GATHER, bool RELU_BF16, bool FUSE_TR>
__global__ __launch_bounds__(256) void gemm_kernel(
    const u16* __restrict__ A,         // [*, KDIM] bf16 rows
    const u16* __restrict__ Bt,        // [NE][n_total][KDIM] bf16
    const int* __restrict__ pair_token,
    const int* __restrict__ seg_off, const int* __restrict__ seg_cnt,
    const int* __restrict__ tl_e, const int* __restrict__ tl_mt,
    u16* __restrict__ out_b,           // act (RELU_BF16)
    float* __restrict__ out_f,         // Ypart (!RELU_BF16)
    int n_total, int nt_mask, int sp_shift, int ks,
    const float* __restrict__ tr_src, u16* __restrict__ tr_dst) {
  __shared__ __align__(16) char smem[16640];
  if (FUSE_TR && blockIdx.z > 0) {
    int flat = (blockIdx.z - 1) * 1152 + blockIdx.y * 16 + blockIdx.x;
    if (flat < 2048) {
      const int R = DF, C = DM;
      float(*t)[65] = (float(*)[65])smem;
      int tid = threadIdx.x;
      int e = flat >> 8;
      int cb = (flat & 7) * 64, rb = ((flat >> 3) & 31) * 64;
      const float* s = tr_src + (size_t)e * R * C;
      u16* d = tr_dst + (size_t)e * R * C;
      int r = tid >> 4, cq = tid & 15;
#pragma unroll
      for (int i = 0; i < 4; ++i) {
        float4 v = *(const float4*)&s[(size_t)(rb + r + 16 * i) * C + cb + cq * 4];
        t[r + 16 * i][cq * 4 + 0] = v.x;
        t[r + 16 * i][cq * 4 + 1] = v.y;
        t[r + 16 * i][cq * 4 + 2] = v.z;
        t[r + 16 * i][cq * 4 + 3] = v.w;
      }
      __syncthreads();
      int rq = tid & 15, c0 = tid >> 4;
#pragma unroll
      for (int i = 0; i < 4; ++i) {
        int c = c0 + 16 * i;
        ushort4 o;
        o.x = f2b(t[rq * 4 + 0][c]);
        o.y = f2b(t[rq * 4 + 1][c]);
        o.z = f2b(t[rq * 4 + 2][c]);
        o.w = f2b(t[rq * 4 + 3][c]);
        *(ushort4*)&d[(size_t)(cb + c) * R + rb + rq * 4] = o;
      }
    }
    return;
  }
  const int e = tl_e[blockIdx.y];
  if (e < 0) return;
  const int mt = tl_mt[blockIdx.y];
  const int cnt = seg_cnt[e];
  const int off = seg_off[e];
  const int nt = blockIdx.x & nt_mask;
  const int sp = blockIdx.x >> sp_shift;
  const int kb = sp * ks, ke = kb + ks;
  const int tid = threadIdx.x;
  const int wave = tid >> 6, lane = tid & 63;

  u16* Al = (u16*)smem;            // [128][32] bf16
  u16* Bl = (u16*)(smem + 8192);   // [128][32] bf16

  const int r0 = wave * 32;
  const int rr = lane >> 2;
  const int cc = (lane & 3) * 8;  // element offset (8 bf16 = 16B)

  const u16* aSrc[2];
  const u16* bSrc[2];
  const u16* BtBase = Bt + ((size_t)e * n_total + (size_t)nt * 128) * KDIM;
#pragma unroll
  for (int g = 0; g < 2; ++g) {
    int rl = r0 + g * 16 + rr;
    int m = mt * 128 + rl;
    if (m > cnt - 1) m = cnt - 1;  // clamp padding rows to valid data
    int srow = GATHER ? pair_token[off + m] : (off + m);
    aSrc[g] = A + (size_t)srow * KDIM + cc;
    bSrc[g] = BtBase + (size_t)rl * KDIM + cc;
  }

  const int wm = wave >> 1, wn = wave & 1;
  const int rl16 = lane & 15;
  const int kk = (lane >> 4) * 8;

  f32x4 acc[4][4];
#pragma unroll
  for (int i = 0; i < 4; ++i)
#pragma unroll
    for (int j = 0; j < 4; ++j)
#pragma unroll
      for (int r = 0; r < 4; ++r) acc[i][j][r] = 0.0f;

  for (int k0 = kb; k0 < ke; k0 += 32) {
#pragma unroll
    for (int g = 0; g < 2; ++g) {
      gl_lds16(aSrc[g] + k0, &Al[(r0 + g * 16) * 32]);
      gl_lds16(bSrc[g] + k0, &Bl[(r0 + g * 16) * 32]);
    }
    __syncthreads();
    short8 af[4], bf[4];
#pragma unroll
    for (int mi = 0; mi < 4; ++mi)
      af[mi] = *(const short8*)&Al[(wm * 64 + mi * 16 + rl16) * 32 + kk];
#pragma unroll
    for (int ni = 0; ni < 4; ++ni)
      bf[ni] = *(const short8*)&Bl[(wn * 64 + ni * 16 + rl16) * 32 + kk];
#pragma unroll
    for (int mi = 0; mi < 4; ++mi)
#pragma unroll
      for (int ni = 0; ni < 4; ++ni)
        acc[mi][ni] = __builtin_amdgcn_mfma_f32_16x16x32_bf16(af[mi], bf[ni], acc[mi][ni], 0, 0, 0);
    __syncthreads();
  }

  float* outp = RELU_BF16 ? nullptr : (out_f + (size_t)sp * NPAIR * DM);

  // epilogue: D[row][col]: col = lane&15, row = (lane>>4)*4 + reg
  const int rowq = (lane >> 4) * 4;
#pragma unroll
  for (int mi = 0; mi < 4; ++mi) {
#pragma unroll
    for (int r = 0; r < 4; ++r) {
      int m = mt * 128 + wm * 64 + mi * 16 + rowq + r;
      if (m < cnt) {
        size_t rowp = (size_t)(off + m) * n_total;
#pragma unroll
        for (int ni = 0; ni < 4; ++ni) {
          int n = nt * 128 + wn * 64 + ni * 16 + rl16;
          float v = acc[mi][ni][r];
          if (RELU_BF16) {
            v = v > 0.0f ? v : 0.0f;
            out_b[rowp + n] = f2b(v);
          } else {
            outp[rowp + n] = v;
          }
        }
      }
    }
  }
}

// ---------------- combine (proven, f32 partials) ----------------
__global__ void combine_kernel(const float* __restrict__ hidden,
                               const float* __restrict__ prob,
                               const int* __restrict__ pair_pos,
                               const float* __restrict__ Ypart,
                               float* __restrict__ out, int nsplit) {
  int i = blockIdx.x * 256 + threadIdx.x;  // group of 4 floats
  int t = i >> 7;                          // 128 groups per token (512/4)
  int g = i & 127;
  int p0 = pair_pos[2 * t], p1 = pair_pos[2 * t + 1];
  float c0 = 0.5f * prob[2 * t];
  float c1 = 0.25f * prob[2 * t + 1];
  float4 a = {0.f, 0.f, 0.f, 0.f}, b = {0.f, 0.f, 0.f, 0.f};
  for (int s = 0; s < nsplit; ++s) {
    const float4* Y = (const float4*)(Ypart + (size_t)s * NPAIR * DM);
    float4 va = Y[(size_t)p0 * 128 + g];
    float4 vb = Y[(size_t)p1 * 128 + g];
    a.x += va.x; a.y += va.y; a.z += va.z; a.w += va.w;
    b.x += vb.x; b.y += vb.y; b.z += vb.z; b.w += vb.w;
  }
  float4 h = ((const float4*)hidden)[i];
  float4 r, o;
  r.x = c0 * a.x + c1 * b.x;
  r.y = c0 * a.y + c1 * b.y;
  r.z = c0 * a.z + c1 * b.z;
  r.w = c0 * a.w + c1 * b.w;
  o.x = (r.x != 0.0f) ? r.x : h.x;
  o.y = (r.y != 0.0f) ? r.y : h.y;
  o.z = (r.z != 0.0f) ? r.z : h.z;
  o.w = (r.w != 0.0f) ? r.w : h.w;
  ((float4*)out)[i] = o;
}

extern "C" void kernel_launch(void* const* d_in, const int* in_sizes, int n_in,
                              void* d_out, int out_size, void* d_ws, size_t ws_size,
                              hipStream_t stream) {
  const float* hidden = (const float*)d_in[0];
  const float* prob = (const float*)d_in[1];
  const float* wi = (const float*)d_in[2];
  const float* wo = (const float*)d_in[3];
  const int* eidx = (const int*)d_in[4];
  float* out = (float*)d_out;

  // proven workspace layout (split=4, f32 partials)
  char* ws = (char*)d_ws;
  u16* hidden_b = (u16*)(ws + 0);                     //  4 MB [4096][512] bf16
  u16* wi_t = (u16*)(ws + ((size_t)4 << 20));         // 16 MB [8][2048][512] bf16 (wi^T)
  u16* wo_t = (u16*)(ws + ((size_t)20 << 20));        // 16 MB [8][512][2048] bf16 (wo^T)
  u16* act = (u16*)(ws + ((size_t)36 << 20));         // 32 MB [8192][2048] bf16
  float* Ypart = (float*)(ws + ((size_t)68 << 20));   // 64 MB [4][8192][512] f32
  char* smalls = ws + ((size_t)132 << 20);
  int* pair_token = (int*)(smalls);
  int* pair_pos = (int*)(smalls + (64u << 10));
  int* seg_off = (int*)(smalls + (128u << 10));
  int* seg_cnt = (int*)(smalls + (128u << 10) + 256);
  int* tl_e = (int*)(smalls + (129u << 10));          // 128 ints
  int* tl_mt = (int*)(smalls + (129u << 10) + 512);   // 128 ints

  // 1) prep: routing+tilelist | hidden cvt | tr wi (wo transpose moved to GEMM1)
  hipLaunchKernelGGL(prep_kernel, dim3(4097), dim3(256), 0, stream,
                     eidx, hidden, hidden_b, wi, wi_t,
                     pair_token, pair_pos, seg_off, seg_cnt, tl_e, tl_mt);
  // 2) GEMM1 (z=0): act = relu(hidden @ wi[e]); K=512, N=2048; tile list (y=72)
  //    + fused wo transpose on z in {1,2} (2048 tiles), done before GEMM2 starts
  hipLaunchKernelGGL((gemm_kernel<DM, true, true, true>), dim3(16, 72, 3), dim3(256), 0, stream,
                     hidden_b, wi_t, pair_token, seg_off, seg_cnt, tl_e, tl_mt,
                     act, (float*)nullptr, DF, 15, 4, DM, wo, wo_t);
  // 3) GEMM2: Ypart[sp] = act @ wo[e] (f32 partials); K=2048 split 4; tile list
  hipLaunchKernelGGL((gemm_kernel<DF, false, false, false>), dim3(4 * SPLIT, 72, 1), dim3(256), 0, stream,
                     act, wo_t, (const int*)nullptr, seg_off, seg_cnt, tl_e, tl_mt,
                     (u16*)nullptr, Ypart, DM, 3, 2, DF / SPLIT,
                     (const float*)nullptr, (u16*)nullptr);
  // 4) combine + where(next!=0, next, hidden)
  hipLaunchKernelGGL(combine_kernel, dim3(2048), dim3(256), 0, stream,
                     hidden, prob, pair_pos, Ypart, out, SPLIT);
}

// Round 11
// 215.447 us; speedup vs baseline: 1.1963x; 1.0205x over previous
//
#include <hip/hip_runtime.h>
#include <cstdint>
#include <cstddef>

#define TOKENS 4096
#define DM 512
#define DF 2048
#define NE 8
#define NPAIR 8192  // TOKENS * TOPK
#define SPLIT 4     // split-K factor for GEMM2 (f32 partials, proven)

typedef unsigned short u16;
typedef __attribute__((ext_vector_type(8))) short short8;
typedef __attribute__((ext_vector_type(4))) float f32x4;

// fp32 -> bf16 round-to-nearest-even (finite inputs only)
__device__ __forceinline__ u16 f2b(float x) {
  uint32_t u = __builtin_bit_cast(uint32_t, x);
  uint32_t r = (u + 0x7fffu + ((u >> 16) & 1u)) >> 16;
  return (u16)r;
}

__device__ __forceinline__ void gl_lds16(const void* gsrc, void* ldst) {
  __builtin_amdgcn_global_load_lds(
      (__attribute__((address_space(1))) void*)(gsrc),
      (__attribute__((address_space(3))) void*)(ldst), 16, 0, 0);
}

// ---------------- prep: routing+tilelist | hidden cvt | tr wi (R10-verbatim) ----
__global__ __launch_bounds__(256) void prep_kernel(
    const int* __restrict__ eidx, const float* __restrict__ hidden, u16* __restrict__ hidden_b,
    const float* __restrict__ wi, u16* __restrict__ wi_t,
    int* __restrict__ pair_token, int* __restrict__ pair_pos,
    int* __restrict__ seg_off, int* __restrict__ seg_cnt,
    int* __restrict__ tl_e, int* __restrict__ tl_mt) {
  __shared__ __align__(16) float t[64][65];
  int bid = blockIdx.x;
  int tid = threadIdx.x;
  if (bid == 0) {
    int* cnt = (int*)&t[0][0];
    int* off = cnt + 8;
    int* cur = cnt + 16;
    if (tid < NE) { cnt[tid] = 0; cur[tid] = 0; }
    __syncthreads();
    for (int i = tid; i < NPAIR; i += 256) atomicAdd(&cnt[eidx[i]], 1);
    __syncthreads();
    if (tid == 0) {
      int a = 0;
      for (int e = 0; e < NE; ++e) { off[e] = a; a += cnt[e]; }
      int n = 0;
      for (int e = 0; e < NE; ++e) {
        int ntl = (cnt[e] + 127) >> 7;
        for (int m = 0; m < ntl && n < 128; ++m, ++n) { tl_e[n] = e; tl_mt[n] = m; }
      }
      for (; n < 128; ++n) { tl_e[n] = -1; tl_mt[n] = 0; }
    }
    __syncthreads();
    for (int i = tid; i < NPAIR; i += 256) {
      int e = eidx[i];
      int p = off[e] + atomicAdd(&cur[e], 1);
      pair_token[p] = i >> 1;  // token index
      pair_pos[i] = p;         // where this (token,k) landed
    }
    if (tid < NE) { seg_off[tid] = off[tid]; seg_cnt[tid] = cnt[tid]; }
  } else if (bid <= 2048) {
    int i = (bid - 1) * 256 + tid;  // float4 group
    float4 v = ((const float4*)hidden)[i];
    ushort4 o;
    o.x = f2b(v.x); o.y = f2b(v.y); o.z = f2b(v.z); o.w = f2b(v.w);
    ((ushort4*)hidden_b)[i] = o;
  } else {
    const int R = DM, C = DF;
    int f = bid - 2049;
    int e = f >> 8;
    int cb = (f & 31) * 64, rb = ((f >> 5) & 7) * 64;
    const float* s = wi + (size_t)e * R * C;
    u16* d = wi_t + (size_t)e * R * C;
    int r = tid >> 4, cq = tid & 15;
#pragma unroll
    for (int i = 0; i < 4; ++i) {
      float4 v = *(const float4*)&s[(size_t)(rb + r + 16 * i) * C + cb + cq * 4];
      t[r + 16 * i][cq * 4 + 0] = v.x;
      t[r + 16 * i][cq * 4 + 1] = v.y;
      t[r + 16 * i][cq * 4 + 2] = v.z;
      t[r + 16 * i][cq * 4 + 3] = v.w;
    }
    __syncthreads();
    int rq = tid & 15, c0 = tid >> 4;
#pragma unroll
    for (int i = 0; i < 4; ++i) {
      int c = c0 + 16 * i;
      ushort4 o;
      o.x = f2b(t[rq * 4 + 0][c]);
      o.y = f2b(t[rq * 4 + 1][c]);
      o.z = f2b(t[rq * 4 + 2][c]);
      o.w = f2b(t[rq * 4 + 3][c]);
      *(ushort4*)&d[(size_t)(cb + c) * R + rb + rq * 4] = o;
    }
  }
}

// ---------------- grouped GEMM, BK=64 XOR-swizzled K-loop, fused tr_wo z-planes ----
// z == 0: C[m][n] = sum_{k in [sp*ks, +ks)} A[row(m)][k] * Bt[n][k]; 128x128, 4 waves.
//   LDS tile [128 rows][64 k], chunk-swizzled: LDS[row][c] = G[row][c ^ (row&7)]
//   (c = 16B chunk index 0..7). Staging: wave covers rows [wave*32,+32) in 4 groups
//   of 8 rows; lane -> row 8g + (lane>>3), chunk cidx = lane&7; source chunk
//   cidx^rsub (rsub = lane>>3 = row&7). Frag read of G[row][j] (j = q+4h,
//   q = lane>>4) at LDS[row][j ^ (row&7)]; row&7 == rl16&7 since all row bases
//   are multiples of 16. K-order of MFMA accumulation identical to BK=32.
// z >= 1 (FUSE_TR): 2048 tr tiles for wo (R10-verbatim body).
template <int KDIM, bool GATHER, bool RELU_BF16, bool FUSE_TR>
__global__ __launch_bounds__(256) void gemm_kernel(
    const u16* __restrict__ A,         // [*, KDIM] bf16 rows
    const u16* __restrict__ Bt,        // [NE][n_total][KDIM] bf16
    const int* __restrict__ pair_token,
    const int* __restrict__ seg_off, const int* __restrict__ seg_cnt,
    const int* __restrict__ tl_e, const int* __restrict__ tl_mt,
    u16* __restrict__ out_b,           // act (RELU_BF16)
    float* __restrict__ out_f,         // Ypart (!RELU_BF16)
    int n_total, int nt_mask, int sp_shift, int ks,
    const float* __restrict__ tr_src, u16* __restrict__ tr_dst) {
  __shared__ __align__(16) char smem[32768];
  if (FUSE_TR && blockIdx.z > 0) {
    int flat = (blockIdx.z - 1) * 1152 + blockIdx.y * 16 + blockIdx.x;
    if (flat < 2048) {
      const int R = DF, C = DM;
      float(*t)[65] = (float(*)[65])smem;
      int tid = threadIdx.x;
      int e = flat >> 8;
      int cb = (flat & 7) * 64, rb = ((flat >> 3) & 31) * 64;
      const float* s = tr_src + (size_t)e * R * C;
      u16* d = tr_dst + (size_t)e * R * C;
      int r = tid >> 4, cq = tid & 15;
#pragma unroll
      for (int i = 0; i < 4; ++i) {
        float4 v = *(const float4*)&s[(size_t)(rb + r + 16 * i) * C + cb + cq * 4];
        t[r + 16 * i][cq * 4 + 0] = v.x;
        t[r + 16 * i][cq * 4 + 1] = v.y;
        t[r + 16 * i][cq * 4 + 2] = v.z;
        t[r + 16 * i][cq * 4 + 3] = v.w;
      }
      __syncthreads();
      int rq = tid & 15, c0 = tid >> 4;
#pragma unroll
      for (int i = 0; i < 4; ++i) {
        int c = c0 + 16 * i;
        ushort4 o;
        o.x = f2b(t[rq * 4 + 0][c]);
        o.y = f2b(t[rq * 4 + 1][c]);
        o.z = f2b(t[rq * 4 + 2][c]);
        o.w = f2b(t[rq * 4 + 3][c]);
        *(ushort4*)&d[(size_t)(cb + c) * R + rb + rq * 4] = o;
      }
    }
    return;
  }
  const int e = tl_e[blockIdx.y];
  if (e < 0) return;
  const int mt = tl_mt[blockIdx.y];
  const int cnt = seg_cnt[e];
  const int off = seg_off[e];
  const int nt = blockIdx.x & nt_mask;
  const int sp = blockIdx.x >> sp_shift;
  const int kb = sp * ks;
  const int tid = threadIdx.x;
  const int wave = tid >> 6, lane = tid & 63;

  u16* Al = (u16*)smem;             // [128][64] bf16, chunk-swizzled
  u16* Bl = (u16*)(smem + 16384);   // [128][64] bf16, chunk-swizzled

  const int r0 = wave * 32;
  const int cidx = lane & 7;           // 16B chunk slot in LDS row
  const int rsub = lane >> 3;          // row & 7 within 8-row group
  const int csrc = (cidx ^ rsub) * 8;  // swizzled source chunk (elements)

  const u16* aSrc[4];
  const u16* bSrc[4];
  u16* aDst[4];
  u16* bDst[4];
  const u16* BtBase = Bt + ((size_t)e * n_total + (size_t)nt * 128) * KDIM;
#pragma unroll
  for (int g = 0; g < 4; ++g) {
    int rl = r0 + 8 * g + rsub;
    int m = mt * 128 + rl;
    if (m > cnt - 1) m = cnt - 1;  // clamp padding rows to valid data
    int srow = GATHER ? pair_token[off + m] : (off + m);
    aSrc[g] = A + (size_t)srow * KDIM + csrc;
    bSrc[g] = BtBase + (size_t)rl * KDIM + csrc;
    aDst[g] = Al + (r0 + 8 * g) * 64;
    bDst[g] = Bl + (r0 + 8 * g) * 64;
  }

  const int wm = wave >> 1, wn = wave & 1;
  const int rl16 = lane & 15;
  const int q = lane >> 4;   // k-chunk quad of the MFMA fragment
  const int rx = rl16 & 7;   // row & 7 (un-swizzle key)

  f32x4 acc[4][4];
#pragma unroll
  for (int i = 0; i < 4; ++i)
#pragma unroll
    for (int j = 0; j < 4; ++j)
#pragma unroll
      for (int r = 0; r < 4; ++r) acc[i][j][r] = 0.0f;

  for (int k0 = kb; k0 < kb + ks; k0 += 64) {
#pragma unroll
    for (int g = 0; g < 4; ++g) {
      gl_lds16(aSrc[g] + k0, aDst[g]);
      gl_lds16(bSrc[g] + k0, bDst[g]);
    }
    __syncthreads();
#pragma unroll
    for (int half = 0; half < 2; ++half) {
      const int jofs = ((q + 4 * half) ^ rx) * 8;  // un-swizzled chunk position
      short8 af[4], bf[4];
#pragma unroll
      for (int mi = 0; mi < 4; ++mi)
        af[mi] = *(const short8*)&Al[(wm * 64 + mi * 16 + rl16) * 64 + jofs];
#pragma unroll
      for (int ni = 0; ni < 4; ++ni)
        bf[ni] = *(const short8*)&Bl[(wn * 64 + ni * 16 + rl16) * 64 + jofs];
#pragma unroll
      for (int mi = 0; mi < 4; ++mi)
#pragma unroll
        for (int ni = 0; ni < 4; ++ni)
          acc[mi][ni] = __builtin_amdgcn_mfma_f32_16x16x32_bf16(af[mi], bf[ni], acc[mi][ni], 0, 0, 0);
    }
    __syncthreads();
  }

  float* outp = RELU_BF16 ? nullptr : (out_f + (size_t)sp * NPAIR * DM);

  // epilogue: D[row][col]: col = lane&15, row = (lane>>4)*4 + reg
  const int rowq = (lane >> 4) * 4;
#pragma unroll
  for (int mi = 0; mi < 4; ++mi) {
#pragma unroll
    for (int r = 0; r < 4; ++r) {
      int m = mt * 128 + wm * 64 + mi * 16 + rowq + r;
      if (m < cnt) {
        size_t rowp = (size_t)(off + m) * n_total;
#pragma unroll
        for (int ni = 0; ni < 4; ++ni) {
          int n = nt * 128 + wn * 64 + ni * 16 + rl16;
          float v = acc[mi][ni][r];
          if (RELU_BF16) {
            v = v > 0.0f ? v : 0.0f;
            out_b[rowp + n] = f2b(v);
          } else {
            outp[rowp + n] = v;
          }
        }
      }
    }
  }
}

// ---------------- combine (proven, f32 partials) ----------------
__global__ void combine_kernel(const float* __restrict__ hidden,
                               const float* __restrict__ prob,
                               const int* __restrict__ pair_pos,
                               const float* __restrict__ Ypart,
                               float* __restrict__ out, int nsplit) {
  int i = blockIdx.x * 256 + threadIdx.x;  // group of 4 floats
  int t = i >> 7;                          // 128 groups per token (512/4)
  int g = i & 127;
  int p0 = pair_pos[2 * t], p1 = pair_pos[2 * t + 1];
  float c0 = 0.5f * prob[2 * t];
  float c1 = 0.25f * prob[2 * t + 1];
  float4 a = {0.f, 0.f, 0.f, 0.f}, b = {0.f, 0.f, 0.f, 0.f};
  for (int s = 0; s < nsplit; ++s) {
    const float4* Y = (const float4*)(Ypart + (size_t)s * NPAIR * DM);
    float4 va = Y[(size_t)p0 * 128 + g];
    float4 vb = Y[(size_t)p1 * 128 + g];
    a.x += va.x; a.y += va.y; a.z += va.z; a.w += va.w;
    b.x += vb.x; b.y += vb.y; b.z += vb.z; b.w += vb.w;
  }
  float4 h = ((const float4*)hidden)[i];
  float4 r, o;
  r.x = c0 * a.x + c1 * b.x;
  r.y = c0 * a.y + c1 * b.y;
  r.z = c0 * a.z + c1 * b.z;
  r.w = c0 * a.w + c1 * b.w;
  o.x = (r.x != 0.0f) ? r.x : h.x;
  o.y = (r.y != 0.0f) ? r.y : h.y;
  o.z = (r.z != 0.0f) ? r.z : h.z;
  o.w = (r.w != 0.0f) ? r.w : h.w;
  ((float4*)out)[i] = o;
}

extern "C" void kernel_launch(void* const* d_in, const int* in_sizes, int n_in,
                              void* d_out, int out_size, void* d_ws, size_t ws_size,
                              hipStream_t stream) {
  const float* hidden = (const float*)d_in[0];
  const float* prob = (const float*)d_in[1];
  const float* wi = (const float*)d_in[2];
  const float* wo = (const float*)d_in[3];
  const int* eidx = (const int*)d_in[4];
  float* out = (float*)d_out;

  // proven workspace layout (split=4, f32 partials)
  char* ws = (char*)d_ws;
  u16* hidden_b = (u16*)(ws + 0);                     //  4 MB [4096][512] bf16
  u16* wi_t = (u16*)(ws + ((size_t)4 << 20));         // 16 MB [8][2048][512] bf16 (wi^T)
  u16* wo_t = (u16*)(ws + ((size_t)20 << 20));        // 16 MB [8][512][2048] bf16 (wo^T)
  u16* act = (u16*)(ws + ((size_t)36 << 20));         // 32 MB [8192][2048] bf16
  float* Ypart = (float*)(ws + ((size_t)68 << 20));   // 64 MB [4][8192][512] f32
  char* smalls = ws + ((size_t)132 << 20);
  int* pair_token = (int*)(smalls);
  int* pair_pos = (int*)(smalls + (64u << 10));
  int* seg_off = (int*)(smalls + (128u << 10));
  int* seg_cnt = (int*)(smalls + (128u << 10) + 256);
  int* tl_e = (int*)(smalls + (129u << 10));          // 128 ints
  int* tl_mt = (int*)(smalls + (129u << 10) + 512);   // 128 ints

  // 1) prep: routing+tilelist | hidden cvt | tr wi
  hipLaunchKernelGGL(prep_kernel, dim3(4097), dim3(256), 0, stream,
                     eidx, hidden, hidden_b, wi, wi_t,
                     pair_token, pair_pos, seg_off, seg_cnt, tl_e, tl_mt);
  // 2) GEMM1 (z=0): act = relu(hidden @ wi[e]); K=512, N=2048; tile list (y=72)
  //    + fused wo transpose on z in {1,2} (2048 tiles)
  hipLaunchKernelGGL((gemm_kernel<DM, true, true, true>), dim3(16, 72, 3), dim3(256), 0, stream,
                     hidden_b, wi_t, pair_token, seg_off, seg_cnt, tl_e, tl_mt,
                     act, (float*)nullptr, DF, 15, 4, DM, wo, wo_t);
  // 3) GEMM2: Ypart[sp] = act @ wo[e] (f32 partials); K=2048 split 4; tile list
  hipLaunchKernelGGL((gemm_kernel<DF, false, false, false>), dim3(4 * SPLIT, 72, 1), dim3(256), 0, stream,
                     act, wo_t, (const int*)nullptr, seg_off, seg_cnt, tl_e, tl_mt,
                     (u16*)nullptr, Ypart, DM, 3, 2, DF / SPLIT,
                     (const float*)nullptr, (u16*)nullptr);
  // 4) combine + where(next!=0, next, hidden)
  hipLaunchKernelGGL(combine_kernel, dim3(2048), dim3(256), 0, stream,
                     hidden, prob, pair_pos, Ypart, out, SPLIT);
}